// Round 22
// baseline (282.236 us; speedup 1.0000x reference)
//
#include <hip/hip_runtime.h>

#define NPTS    65536
#define DIM     128
#define KCODES  1024
#define BM      64       // points per argmin block (grid 1024 -> 4 blocks/CU)
#define TILE_C  64       // codes per LDS tile (double-buffered 2x16 KB)
#define NTHR    256      // 4 waves; each wave owns 16 points
#define NTILE   (KCODES / TILE_C)   // 16

typedef _Float16 f16x8 __attribute__((ext_vector_type(8)));
typedef float    f32x4 __attribute__((ext_vector_type(4)));

__device__ __forceinline__ void gload_lds16(const void* g, void* l) {
    __builtin_amdgcn_global_load_lds(
        (const __attribute__((address_space(1))) void*)g,
        (__attribute__((address_space(3))) void*)l, 16, 0, 0);
}

// ---------------- Kernel P: pack codebook -> fp16 frag-order + halfnorm(rounded)
// 64 blocks x 256. g in 0..16383: tc=g>>10 (tile of 64 codes), f=(g>>6)&15,
// l=g&63; f = nt*4+akk ; l = hg*16+n ; code c = tc*64+nt*16+n ; d0 = akk*32+hg*8.
__global__ __launch_bounds__(256)
void pack_kernel(const float* __restrict__ embed, _Float16* __restrict__ ebf,
                 float* __restrict__ hn)
{
    __shared__ float partial[256];
    const int t = threadIdx.x;
    const int b = blockIdx.x;
    const int g = b * 256 + t;                       // 0..16383

    const int tc  = g >> 10;
    const int f   = (g >> 6) & 15;
    const int l   = g & 63;
    const int nt  = f >> 2;
    const int akk = f & 3;
    const int hg  = l >> 4;
    const int n   = l & 15;
    const int c   = tc * TILE_C + nt * 16 + n;
    const int d0  = akk * 32 + hg * 8;
    const float* src = embed + (long)c * DIM + d0;
    float4 v0 = *reinterpret_cast<const float4*>(src);
    float4 v1 = *reinterpret_cast<const float4*>(src + 4);
    float vv[8] = {v0.x, v0.y, v0.z, v0.w, v1.x, v1.y, v1.z, v1.w};
    f16x8 out;
    float ss = 0.f;
    #pragma unroll
    for (int j = 0; j < 8; ++j) {
        _Float16 h = (_Float16)vv[j];                // RNE
        out[j] = h;
        float r = (float)h;                          // halfnorm from ROUNDED values
        ss += r * r;
    }
    *reinterpret_cast<f16x8*>(ebf + (long)g * 8) = out;

    // block b holds 16 complete code rows (tc=b>>2, nt=b&3)
    partial[t] = ss;
    __syncthreads();
    if (t < 16) {
        float s = 0.f;
        #pragma unroll
        for (int k = 0; k < 16; ++k) s += partial[t + k * 16];
        hn[(b >> 2) * TILE_C + (b & 3) * 16 + t] = 0.5f * s;
    }
}

// ---------------- Kernel 1: MFMA fp16 argmin over FULL codebook ----------------
// grid 1024 (BM=64). Writes ONLY ind (quantize/hist moved to codesum).
__global__ __launch_bounds__(NTHR, 4)
void argmin_kernel(const float* __restrict__ x, const _Float16* __restrict__ ebf,
                   const float* __restrict__ halfnorm, int* __restrict__ ind)
{
    __shared__ _Float16 es[2][8192];    // 2 x 16 KB double-buffered tile

    const int t    = threadIdx.x;
    const int lane = t & 63;
    const int w    = t >> 6;           // wave 0..3, owns 16 points
    const int r16  = lane & 15;
    const int h4   = lane >> 4;
    const long xbase = (long)blockIdx.x * BM * DIM;
    const int  wp    = w * 16;

    // ---- A fragments: row (wp + r16), fp16 ----
    f16x8 a[4];
    {
        const long prow = xbase + (long)(wp + r16) * DIM;
        #pragma unroll
        for (int akk = 0; akk < 4; ++akk) {
            const float* s = x + prow + akk * 32 + h4 * 8;
            float4 u0 = *reinterpret_cast<const float4*>(s);
            float4 u1 = *reinterpret_cast<const float4*>(s + 4);
            float vv[8] = {u0.x, u0.y, u0.z, u0.w, u1.x, u1.y, u1.z, u1.w};
            #pragma unroll
            for (int j = 0; j < 8; ++j) a[akk][j] = (_Float16)vv[j];
        }
    }

    // ---- prologue: stage tile 0 (wave w loads frags w*4..w*4+3, 1 KB each) ----
    #pragma unroll
    for (int i = 0; i < 4; ++i) {
        const int f = w * 4 + i;
        gload_lds16(ebf + (long)f * 512 + lane * 8, &es[0][f * 512]);
    }
    float hnv_cur[4], hnv_nxt[4];
    #pragma unroll
    for (int nt = 0; nt < 4; ++nt) hnv_cur[nt] = halfnorm[nt * 16 + r16];
    __syncthreads();   // tile 0 resident

    float bestv[4];
    int   besti[4];
    #pragma unroll
    for (int s = 0; s < 4; ++s) { bestv[s] = -1e30f; besti[s] = 0; }

    #pragma unroll 1
    for (int tile = 0; tile < NTILE; ++tile) {
        // issue next tile's stage + next halfnorms (latency hides under MFMA)
        if (tile + 1 < NTILE) {
            const long gbase = (long)(tile + 1) * 8192;
            #pragma unroll
            for (int i = 0; i < 4; ++i) {
                const int f = w * 4 + i;
                gload_lds16(ebf + gbase + f * 512 + lane * 8, &es[(tile + 1) & 1][f * 512]);
            }
            #pragma unroll
            for (int nt = 0; nt < 4; ++nt)
                hnv_nxt[nt] = halfnorm[(tile + 1) * TILE_C + nt * 16 + r16];
        }

        f32x4 C[4];
        #pragma unroll
        for (int nt = 0; nt < 4; ++nt) C[nt] = (f32x4){0.f, 0.f, 0.f, 0.f};

        #pragma unroll
        for (int akk = 0; akk < 4; ++akk) {
            #pragma unroll
            for (int nt = 0; nt < 4; ++nt) {
                f16x8 B = *reinterpret_cast<const f16x8*>(
                    &es[tile & 1][(nt * 4 + akk) * 512 + lane * 8]);
                C[nt] = __builtin_amdgcn_mfma_f32_16x16x32_f16(a[akk], B, C[nt], 0, 0, 0);
            }
        }

        // ---- scores + running argmax (codes ascending: tile asc, nt asc) ----
        #pragma unroll
        for (int nt = 0; nt < 4; ++nt) {
            const int c = tile * TILE_C + nt * 16 + r16;
            #pragma unroll
            for (int reg = 0; reg < 4; ++reg) {
                float sc = C[nt][reg] - hnv_cur[nt];
                if (sc > bestv[reg]) { bestv[reg] = sc; besti[reg] = c; }
            }
        }
        #pragma unroll
        for (int nt = 0; nt < 4; ++nt) hnv_cur[nt] = hnv_nxt[nt];
        __syncthreads();   // next tile resident; current tile readers done
    }

    // ---- butterfly reduce across 16 columns, tie -> smaller idx ----
    #pragma unroll
    for (int s = 0; s < 4; ++s) {
        float v = bestv[s];
        int   i = besti[s];
        #pragma unroll
        for (int off = 1; off < 16; off <<= 1) {
            float ov = __shfl_xor(v, off);
            int   oi = __shfl_xor(i, off);
            if (ov > v || (ov == v && oi < i)) { v = ov; i = oi; }
        }
        bestv[s] = v; besti[s] = i;
    }
    if (r16 == 0) {
        #pragma unroll
        for (int s = 0; s < 4; ++s) {
            int p = wp + h4 * 4 + s;     // point = row (h4*4 + reg)
            ind[blockIdx.x * BM + p] = besti[s];
        }
    }
}

// ---------------- Kernel S: code-centric scan-sum + quantize + EMA -------------
// Block c scans the full ind array (L2-resident), ballot-matches code c:
// gathers/sums x rows, writes quantize rows (= embed[c]), then fused EMA.
__global__ __launch_bounds__(256)
void codesum_kernel(const float* __restrict__ x, const int* __restrict__ ind,
                    const float* __restrict__ embed, const float* __restrict__ ema_embed,
                    const float* __restrict__ ema_num, float* __restrict__ quant,
                    float* __restrict__ embed_new, float* __restrict__ ema_embed_new,
                    float* __restrict__ ema_num_new)
{
    __shared__ float wacc[4][DIM];   // 2 KB
    __shared__ int   wcnt[4];
    const int c    = blockIdx.x;
    const int t    = threadIdx.x;
    const int lane = t & 63;
    const int w    = t >> 6;

    for (int i = t; i < 4 * DIM; i += 256) (&wacc[0][0])[i] = 0.f;

    // preload this code's row (for quantize writes)
    const float er0 = embed[(long)c * DIM + lane];
    const float er1 = embed[(long)c * DIM + 64 + lane];

    int cnt = 0;
    const int base = w * (NPTS / 4);
    #pragma unroll 1
    for (int k = 0; k < NPTS / 4; k += 64) {
        const int v = ind[base + k + lane];
        cnt += (v == c) ? 1 : 0;
        unsigned long long m = __ballot(v == c);
        while (m) {
            const int l = __ffsll((unsigned long long)m) - 1;
            m &= m - 1;
            const long p = base + k + l;
            wacc[w][lane]      += x[p * DIM + lane];
            wacc[w][lane + 64] += x[p * DIM + 64 + lane];
            quant[p * DIM + lane]      = er0;
            quant[p * DIM + 64 + lane] = er1;
        }
    }
    #pragma unroll
    for (int off = 32; off > 0; off >>= 1) cnt += __shfl_xor(cnt, off);
    if (lane == 0) wcnt[w] = cnt;
    __syncthreads();

    if (t < DIM) {
        const float n  = (float)(wcnt[0] + wcnt[1] + wcnt[2] + wcnt[3]);
        const float en = ema_num[c] * 0.8f + 0.2f * n;
        const float s  = wacc[0][t] + wacc[1][t] + wacc[2][t] + wacc[3][t];
        const float ee = ema_embed[(long)c * DIM + t] * 0.8f + 0.2f * s;
        ema_embed_new[(long)c * DIM + t] = ee;
        embed_new[(long)c * DIM + t]     = ee / en;
        if (t == 0) ema_num_new[c] = en;
    }
}

extern "C" void kernel_launch(void* const* d_in, const int* in_sizes, int n_in,
                              void* d_out, int out_size, void* d_ws, size_t ws_size,
                              hipStream_t stream)
{
    const float* x         = (const float*)d_in[0];
    const float* embed     = (const float*)d_in[1];
    const float* ema_embed = (const float*)d_in[2];
    const float* ema_num   = (const float*)d_in[3];

    float* out0 = (float*)d_out;            // quantize      (16*4096*128)
    float* out1 = out0 + 8388608;           // embed_new     (1024*128)
    float* out2 = out1 + 131072;            // ema_embed_new (1024*128)
    float* out3 = out2 + 131072;            // ema_num_new   (1024)

    char* ws = (char*)d_ws;
    float*    hn  = (float*)ws;                 // 4 KB
    _Float16* ebf = (_Float16*)(ws + 4096);     // 256 KB
    int*      ind = (int*)(ws + 266240);        // 256 KB

    pack_kernel<<<64, 256, 0, stream>>>(embed, ebf, hn);
    argmin_kernel<<<NPTS / BM, NTHR, 0, stream>>>(x, ebf, hn, ind);
    codesum_kernel<<<KCODES, 256, 0, stream>>>(x, ind, embed, ema_embed, ema_num,
                                               out0, out1, out2, out3);
}

// Round 24
// 272.496 us; speedup vs baseline: 1.0357x; 1.0357x over previous
//
#include <hip/hip_runtime.h>
#include <hip/hip_cooperative_groups.h>

namespace cg = cooperative_groups;

#define NPTS    65536
#define DIM     128
#define KCODES  1024
#define BM      128      // points per block (grid 512 = 2 blocks/CU x 256 CUs)
#define TILE_C  64       // codes per LDS tile (double-buffered 2x16 KB)
#define NTHR    512      // 8 waves; each wave owns 16 points
#define NTILE   (KCODES / TILE_C)   // 16
#define NBLK    (NPTS / BM)         // 512

typedef _Float16 f16x8 __attribute__((ext_vector_type(8)));
typedef float    f32x4 __attribute__((ext_vector_type(4)));

__device__ __forceinline__ void gload_lds16(const void* g, void* l) {
    __builtin_amdgcn_global_load_lds(
        (const __attribute__((address_space(1))) void*)g,
        (__attribute__((address_space(3))) void*)l, 16, 0, 0);
}

// ---------------- Kernel P: pack codebook -> fp16 frag-order + halfnorm(rounded)
//                  + init acc (=0.8*ema_embed) + zero ghist/gcursor -------------
__global__ __launch_bounds__(256)
void pack_kernel(const float* __restrict__ embed, _Float16* __restrict__ ebf,
                 int* __restrict__ ghist, int* __restrict__ gcursor,
                 const float* __restrict__ ema_embed, float* __restrict__ acc,
                 float* __restrict__ hn)
{
    __shared__ float partial[256];
    const int t = threadIdx.x;
    const int b = blockIdx.x;
    const int g = b * 256 + t;                       // 0..16383
    if (g < KCODES) { ghist[g] = 0; gcursor[g] = 0; }
    {   // init acc = 0.8 * ema_embed (2 float4s per thread = 32768 total)
        float4 e0 = reinterpret_cast<const float4*>(ema_embed)[g];
        float4 e1 = reinterpret_cast<const float4*>(ema_embed)[g + 16384];
        reinterpret_cast<float4*>(acc)[g] =
            (float4){0.8f * e0.x, 0.8f * e0.y, 0.8f * e0.z, 0.8f * e0.w};
        reinterpret_cast<float4*>(acc)[g + 16384] =
            (float4){0.8f * e1.x, 0.8f * e1.y, 0.8f * e1.z, 0.8f * e1.w};
    }

    const int tc  = g >> 10;
    const int f   = (g >> 6) & 15;
    const int l   = g & 63;
    const int nt  = f >> 2;
    const int akk = f & 3;
    const int hg  = l >> 4;
    const int n   = l & 15;
    const int c   = tc * TILE_C + nt * 16 + n;
    const int d0  = akk * 32 + hg * 8;
    const float* src = embed + (long)c * DIM + d0;
    float4 v0 = *reinterpret_cast<const float4*>(src);
    float4 v1 = *reinterpret_cast<const float4*>(src + 4);
    float vv[8] = {v0.x, v0.y, v0.z, v0.w, v1.x, v1.y, v1.z, v1.w};
    f16x8 out;
    float ss = 0.f;
    #pragma unroll
    for (int j = 0; j < 8; ++j) {
        _Float16 h = (_Float16)vv[j];                // RNE
        out[j] = h;
        float r = (float)h;                          // halfnorm from ROUNDED values
        ss += r * r;
    }
    *reinterpret_cast<f16x8*>(ebf + (long)g * 8) = out;

    partial[t] = ss;
    __syncthreads();
    if (t < 16) {
        float s = 0.f;
        #pragma unroll
        for (int k = 0; k < 16; ++k) s += partial[t + k * 16];
        hn[(b >> 2) * TILE_C + (b & 3) * 16 + t] = 0.5f * s;
    }
}

// ===== Shared argmin phase body (512 thr, BM=128), used by both paths ==========
// Computes bidx[] (block-local best codes), writes ind, quantize, ghist.
__device__ __forceinline__
void argmin_phase(const float* __restrict__ x, const _Float16* __restrict__ ebf,
                  const float* __restrict__ halfnorm, const float* __restrict__ embed,
                  int* __restrict__ ind, float* __restrict__ quant,
                  int* __restrict__ ghist,
                  _Float16 (*es)[8192], int* hist, int* bidx)
{
    const int t    = threadIdx.x;
    const int lane = t & 63;
    const int w    = t >> 6;           // wave 0..7, owns 16 points
    const int r16  = lane & 15;
    const int h4   = lane >> 4;
    const int blk  = blockIdx.x;
    const long xbase = (long)blk * BM * DIM;
    const int  wp    = w * 16;

    for (int i = t; i < KCODES; i += NTHR) hist[i] = 0;

    f16x8 a[4];
    {
        const long prow = xbase + (long)(wp + r16) * DIM;
        #pragma unroll
        for (int akk = 0; akk < 4; ++akk) {
            const float* s = x + prow + akk * 32 + h4 * 8;
            float4 u0 = *reinterpret_cast<const float4*>(s);
            float4 u1 = *reinterpret_cast<const float4*>(s + 4);
            float vv[8] = {u0.x, u0.y, u0.z, u0.w, u1.x, u1.y, u1.z, u1.w};
            #pragma unroll
            for (int j = 0; j < 8; ++j) a[akk][j] = (_Float16)vv[j];
        }
    }

    // prologue: stage tile 0 (wave w loads frags w*2, w*2+1; 1 KB each)
    #pragma unroll
    for (int i = 0; i < 2; ++i) {
        const int f = w * 2 + i;
        gload_lds16(ebf + (long)f * 512 + lane * 8, &es[0][f * 512]);
    }
    float hnv_cur[4], hnv_nxt[4];
    #pragma unroll
    for (int nt = 0; nt < 4; ++nt) hnv_cur[nt] = halfnorm[nt * 16 + r16];
    __syncthreads();   // tile 0 resident; hist zeroed

    float bestv[4];
    int   besti[4];
    #pragma unroll
    for (int s = 0; s < 4; ++s) { bestv[s] = -1e30f; besti[s] = 0; }

    #pragma unroll 1
    for (int tile = 0; tile < NTILE; ++tile) {
        if (tile + 1 < NTILE) {
            const long gbase = (long)(tile + 1) * 8192;
            #pragma unroll
            for (int i = 0; i < 2; ++i) {
                const int f = w * 2 + i;
                gload_lds16(ebf + gbase + f * 512 + lane * 8, &es[(tile + 1) & 1][f * 512]);
            }
            #pragma unroll
            for (int nt = 0; nt < 4; ++nt)
                hnv_nxt[nt] = halfnorm[(tile + 1) * TILE_C + nt * 16 + r16];
        }

        f32x4 C[4];
        #pragma unroll
        for (int nt = 0; nt < 4; ++nt) C[nt] = (f32x4){0.f, 0.f, 0.f, 0.f};

        #pragma unroll
        for (int akk = 0; akk < 4; ++akk) {
            #pragma unroll
            for (int nt = 0; nt < 4; ++nt) {
                f16x8 B = *reinterpret_cast<const f16x8*>(
                    &es[tile & 1][(nt * 4 + akk) * 512 + lane * 8]);
                C[nt] = __builtin_amdgcn_mfma_f32_16x16x32_f16(a[akk], B, C[nt], 0, 0, 0);
            }
        }

        #pragma unroll
        for (int nt = 0; nt < 4; ++nt) {
            const int c = tile * TILE_C + nt * 16 + r16;
            #pragma unroll
            for (int reg = 0; reg < 4; ++reg) {
                float sc = C[nt][reg] - hnv_cur[nt];
                if (sc > bestv[reg]) { bestv[reg] = sc; besti[reg] = c; }
            }
        }
        #pragma unroll
        for (int nt = 0; nt < 4; ++nt) hnv_cur[nt] = hnv_nxt[nt];
        __syncthreads();
    }

    #pragma unroll
    for (int s = 0; s < 4; ++s) {
        float v = bestv[s];
        int   i = besti[s];
        #pragma unroll
        for (int off = 1; off < 16; off <<= 1) {
            float ov = __shfl_xor(v, off);
            int   oi = __shfl_xor(i, off);
            if (ov > v || (ov == v && oi < i)) { v = ov; i = oi; }
        }
        bestv[s] = v; besti[s] = i;
    }
    if (r16 == 0) {
        #pragma unroll
        for (int s = 0; s < 4; ++s) {
            int p = wp + h4 * 4 + s;
            bidx[p] = besti[s];
            ind[blk * BM + p] = besti[s];
        }
    }
    __syncthreads();

    if (t < BM) atomicAdd(&hist[bidx[t]], 1);

    {   // quantize: lane-contiguous gather-copy of embed[best]
        float4* dst = reinterpret_cast<float4*>(quant + xbase);
        #pragma unroll
        for (int i = 0; i < 8; ++i) {
            int idx = i * NTHR + t;      // 0..4095
            int p   = idx >> 5;
            int q   = idx & 31;
            int c   = bidx[p];
            dst[idx] = reinterpret_cast<const float4*>(embed + (long)c * DIM)[q];
        }
    }

    __syncthreads();
    for (int i = t; i < KCODES; i += NTHR)
        if (hist[i]) atomicAdd(&ghist[i], hist[i]);
}

// ---------------- Fused cooperative kernel: argmin -> scatter -> sum -> final --
__global__ __launch_bounds__(NTHR, 4)
void fused_kernel(const float* __restrict__ x, const _Float16* __restrict__ ebf,
                  const float* __restrict__ halfnorm, const float* __restrict__ embed,
                  const float* __restrict__ ema_num,
                  float* __restrict__ quant, float* __restrict__ embed_new,
                  float* __restrict__ acc /*= ema_embed_new, pre-inited*/,
                  float* __restrict__ ema_num_new,
                  int* __restrict__ ind, int* __restrict__ ghist,
                  int* __restrict__ gcursor, int* __restrict__ sorted,
                  int* __restrict__ scode)
{
    cg::grid_group grid = cg::this_grid();

    __shared__ _Float16 es[2][8192];    // 32 KB
    __shared__ int      hist[KCODES];   // 4 KB (aliased in phase 3)
    __shared__ int      bidx[BM];
    __shared__ int      wsum[8];

    const int t    = threadIdx.x;
    const int lane = t & 63;
    const int w    = t >> 6;
    const int blk  = blockIdx.x;

    // PHASE 1
    argmin_phase(x, ebf, halfnorm, embed, ind, quant, ghist, es, hist, bidx);

    grid.sync();   // ghist complete

    // PHASE 2: redundant scan + scatter own 128 points
    {
        int* off_lds = reinterpret_cast<int*>(&es[0][0]);   // 4 KB, es dead
        int v[2], pre[2];
        int s = 0;
        #pragma unroll
        for (int j = 0; j < 2; ++j) {
            v[j] = ghist[t * 2 + j];
            pre[j] = s;
            s += v[j];
        }
        int incl = s;
        #pragma unroll
        for (int off = 1; off < 64; off <<= 1) {
            int u = __shfl_up(incl, off);
            if (lane >= off) incl += u;
        }
        if (lane == 63) wsum[w] = incl;
        __syncthreads();
        if (t == 0) {
            int aa = 0;
            #pragma unroll
            for (int k = 0; k < 8; ++k) { int tmp = wsum[k]; wsum[k] = aa; aa += tmp; }
        }
        __syncthreads();
        const int excl = wsum[w] + incl - s;
        #pragma unroll
        for (int j = 0; j < 2; ++j) off_lds[t * 2 + j] = excl + pre[j];
        __syncthreads();

        if (t < BM) {
            const int p = blk * BM + t;
            const int c = bidx[t];
            const int pos = off_lds[c] + atomicAdd(&gcursor[c], 1);
            sorted[pos] = p;
            scode[pos]  = c;
        }
    }

    grid.sync();   // sorted/scode complete

    // PHASE 3: chunk-run-sum over sorted[blk*128 .. +127] (two 64-subchunks)
    {
        int* sp = hist;          // alias (hist dead)
        int* sc = hist + 128;
        const int base = blk * BM;
        __syncthreads();
        if (t < BM) { sp[t] = sorted[base + t]; sc[t] = scode[base + t]; }
        __syncthreads();

        if (t < 256) {
            const int d   = t & 127;
            const int sb  = (t >> 7) * 64;
            float aa = 0.f;
            int cprev = sc[sb];
            #pragma unroll 1
            for (int kk = 0; kk < 8; ++kk) {
                float vv[8];
                #pragma unroll
                for (int i = 0; i < 8; ++i)
                    vv[i] = x[(long)sp[sb + kk * 8 + i] * DIM + d];
                #pragma unroll
                for (int i = 0; i < 8; ++i) {
                    const int c = sc[sb + kk * 8 + i];     // wave-uniform
                    if (c != cprev) {
                        atomicAdd(&acc[(long)cprev * DIM + d], 0.2f * aa);
                        aa = 0.f; cprev = c;
                    }
                    aa += vv[i];
                }
            }
            atomicAdd(&acc[(long)cprev * DIM + d], 0.2f * aa);
        }
    }

    grid.sync();   // acc (= ema_embed_new) complete

    // PHASE 4: finalize 2 codes per block
    if (t < 256) {
        const int c = blk * 2 + (t >> 7);
        const int d = t & 127;
        const float en = ema_num[c] * 0.8f + 0.2f * (float)ghist[c];
        embed_new[(long)c * DIM + d] = acc[(long)c * DIM + d] / en;
        if (d == 0) ema_num_new[c] = en;
    }
}

// ---------------- Fallback chain (R16-proven) ----------------------------------
__global__ __launch_bounds__(NTHR, 4)
void argmin_fb(const float* __restrict__ x, const _Float16* __restrict__ ebf,
               const float* __restrict__ halfnorm, const float* __restrict__ embed,
               int* __restrict__ ind, float* __restrict__ quant,
               int* __restrict__ ghist)
{
    __shared__ _Float16 es[2][8192];
    __shared__ int      hist[KCODES];
    __shared__ int      bidx[BM];
    argmin_phase(x, ebf, halfnorm, embed, ind, quant, ghist, es, hist, bidx);
}

__global__ __launch_bounds__(256)
void scatter_kernel(const int* __restrict__ ghist, const int* __restrict__ ind,
                    const float* __restrict__ ema_num, float* __restrict__ ema_num_new,
                    int* __restrict__ gcursor, int* __restrict__ sorted,
                    int* __restrict__ scode)
{
    __shared__ int off_lds[KCODES];
    __shared__ int wsum[4];
    const int t    = threadIdx.x;
    const int lane = t & 63;
    const int w    = t >> 6;

    int v[4], pre[4];
    int s = 0;
    #pragma unroll
    for (int j = 0; j < 4; ++j) {
        v[j] = ghist[t * 4 + j];
        pre[j] = s;
        s += v[j];
    }
    int incl = s;
    #pragma unroll
    for (int off = 1; off < 64; off <<= 1) {
        int u = __shfl_up(incl, off);
        if (lane >= off) incl += u;
    }
    if (lane == 63) wsum[w] = incl;
    __syncthreads();
    if (t == 0) {
        int a = 0;
        #pragma unroll
        for (int k = 0; k < 4; ++k) { int tmp = wsum[k]; wsum[k] = a; a += tmp; }
    }
    __syncthreads();
    const int excl = wsum[w] + incl - s;
    #pragma unroll
    for (int j = 0; j < 4; ++j) off_lds[t * 4 + j] = excl + pre[j];

    if (blockIdx.x == 0) {
        #pragma unroll
        for (int j = 0; j < 4; ++j)
            ema_num_new[t * 4 + j] = ema_num[t * 4 + j] * 0.8f + 0.2f * (float)v[j];
    }
    __syncthreads();

    const int p = blockIdx.x * 256 + t;
    const int c = ind[p];
    const int pos = off_lds[c] + atomicAdd(&gcursor[c], 1);
    sorted[pos] = p;
    scode[pos]  = c;
}

__global__ __launch_bounds__(128)
void sum2_kernel(const float* __restrict__ x, const int* __restrict__ sorted,
                 const int* __restrict__ scode, float* __restrict__ acc)
{
    __shared__ int sp[64];
    __shared__ int sc[64];
    const int t = threadIdx.x;
    const int base = blockIdx.x * 64;
    if (t < 64) { sp[t] = sorted[base + t]; sc[t] = scode[base + t]; }
    __syncthreads();

    float a = 0.f;
    int cprev = sc[0];
    #pragma unroll 1
    for (int kk = 0; kk < 8; ++kk) {
        float v[8];
        #pragma unroll
        for (int i = 0; i < 8; ++i)
            v[i] = x[(long)sp[kk * 8 + i] * DIM + t];
        #pragma unroll
        for (int i = 0; i < 8; ++i) {
            const int c = sc[kk * 8 + i];
            if (c != cprev) {
                atomicAdd(&acc[(long)cprev * DIM + t], 0.2f * a);
                a = 0.f; cprev = c;
            }
            a += v[i];
        }
    }
    atomicAdd(&acc[(long)cprev * DIM + t], 0.2f * a);
}

__global__ __launch_bounds__(256)
void final_kernel(const float* __restrict__ acc, const float* __restrict__ ema_num_new,
                  float* __restrict__ embed_new)
{
    const int g = blockIdx.x * 256 + threadIdx.x;
    float4 v = reinterpret_cast<const float4*>(acc)[g];
    const float en = ema_num_new[g >> 5];
    float4 o = {v.x / en, v.y / en, v.z / en, v.w / en};
    reinterpret_cast<float4*>(embed_new)[g] = o;
}

extern "C" void kernel_launch(void* const* d_in, const int* in_sizes, int n_in,
                              void* d_out, int out_size, void* d_ws, size_t ws_size,
                              hipStream_t stream)
{
    const float* x         = (const float*)d_in[0];
    const float* embed     = (const float*)d_in[1];
    const float* ema_embed = (const float*)d_in[2];
    const float* ema_num   = (const float*)d_in[3];

    float* out0 = (float*)d_out;            // quantize      (16*4096*128)
    float* out1 = out0 + 8388608;           // embed_new     (1024*128)
    float* out2 = out1 + 131072;            // ema_embed_new (1024*128)
    float* out3 = out2 + 131072;            // ema_num_new   (1024)

    char* ws = (char*)d_ws;
    float*    hn      = (float*)ws;                 // 4 KB
    _Float16* ebf     = (_Float16*)(ws + 4096);     // 256 KB
    int*      ghist   = (int*)(ws + 266240);        // 4 KB
    int*      gcursor = (int*)(ws + 270336);        // 4 KB
    int*      ind     = (int*)(ws + 274432);        // 256 KB
    int*      sorted  = (int*)(ws + 536576);        // 256 KB
    int*      scode   = (int*)(ws + 798720);        // 256 KB

    pack_kernel<<<64, 256, 0, stream>>>(embed, ebf, ghist, gcursor, ema_embed,
                                        out2, hn);

    void* args[] = {
        (void*)&x, (void*)&ebf, (void*)&hn, (void*)&embed, (void*)&ema_num,
        (void*)&out0, (void*)&out1, (void*)&out2, (void*)&out3,
        (void*)&ind, (void*)&ghist, (void*)&gcursor, (void*)&sorted, (void*)&scode
    };
    hipError_t err = hipLaunchCooperativeKernel((const void*)fused_kernel,
                                                dim3(NBLK), dim3(NTHR), args, 0, stream);
    if (err != hipSuccess) {
        // fallback: proven 4-kernel chain (identical results)
        argmin_fb<<<NBLK, NTHR, 0, stream>>>(x, ebf, hn, embed, ind, out0, ghist);
        scatter_kernel<<<NPTS / 256, 256, 0, stream>>>(ghist, ind, ema_num, out3,
                                                       gcursor, sorted, scode);
        sum2_kernel<<<NPTS / 64, 128, 0, stream>>>(x, sorted, scode, out2);
        final_kernel<<<128, 256, 0, stream>>>(out2, out3, out1);
    }
}